// Round 12
// baseline (2772.605 us; speedup 1.0000x reference)
//
#include <hip/hip_runtime.h>
#include <stdint.h>

// 3-layer LSTM (H=64, B=256, S=4096, DIN=1) + linear head.
// One block/batch element; 768 thr = 12 waves = 3 groups x 4 (group=layer),
// skew 2 ticks/layer (l0@T: step T, l1: T-2, l2: T-4, head y: T-5).
// R17: force the act||prefetch-MFMA overlap R16 intended.
// R16 was null because the act sat behind the `if (step...)` BRANCH: LLVM
// schedules per basic block, so act could not interleave with the prefetch
// MFMAs; and issue-order overlap alone didn't happen. Fixes:
//  (1) BRANCHLESS act: all lanes compute unconditionally (inputs finite:
//      LDS zero-init, xrow zero-padded); cc predicated by one v_cndmask;
//      only the h-write / final-store keep masks. -> ds_reads + 16 MFMA +
//      ~45 act VALU live in ONE scheduling region.
//  (2) sched_group_barrier pin: [4 ds_read][8 self MFMA][8 x (1 prefetch
//      MFMA + 5 VALU)] -> act VALU issues between prefetch MFMA issues,
//      matrix pipe and VALU run concurrently inside each wave.
//  (3) head block moved after the act region (its branch no longer splits
//      grp1/2's region).
// Carried: h=A-operand row-replicated MFMA; carried input-side acc (ai) per
// R16; pinned pre-packed B-frags; bias in C regs; y staged 32/store.

#define SQ 4096
#define HH 64
#define NB 256

typedef _Float16 h2    __attribute__((ext_vector_type(2)));
typedef _Float16 f16x8 __attribute__((ext_vector_type(8)));
typedef float    f32x4 __attribute__((ext_vector_type(4)));

__device__ __forceinline__ float frcp(float x)  { return __builtin_amdgcn_rcpf(x); }
__device__ __forceinline__ float fexp2(float x) { return __builtin_amdgcn_exp2f(x); }

__device__ __forceinline__ void pin4(uint4& r) {
    asm volatile("" : "+v"(r.x), "+v"(r.y), "+v"(r.z), "+v"(r.w));
}
__device__ __forceinline__ void pinv(f32x4& r) {
    float t0 = r[0], t1 = r[1], t2 = r[2], t3 = r[3];
    asm volatile("" : "+v"(t0), "+v"(t1), "+v"(t2), "+v"(t3));
    r[0] = t0; r[1] = t1; r[2] = t2; r[3] = t3;
}

// D = A(h, rows replicated) x B(weights) + C
__device__ __forceinline__ f32x4 mm(uint4 hv, uint4 wv, f32x4 c) {
    return __builtin_amdgcn_mfma_f32_16x16x32_f16(
        __builtin_bit_cast(f16x8, hv), __builtin_bit_cast(f16x8, wv), c, 0, 0, 0);
}

// ---- prep: fp32 weights -> MFMA B-fragments (packed fp16 pairs). UNCHANGED.
// Regions: grp0 [0,8192) u32 (Whh0, KT=2); grp1 [8192,24576) ([Wih1|Whh1],
// KT=4); grp2 [24576,40960) ([Wih2|Whh2], KT=4); y-frag [40960,41472).
__global__ __launch_bounds__(256)
void prep_weights(const float* __restrict__ Whh0, const float* __restrict__ Wih1,
                  const float* __restrict__ Whh1, const float* __restrict__ Wih2,
                  const float* __restrict__ Whh2, const float* __restrict__ Wlin,
                  uint32_t* __restrict__ ws)
{
    const int idx = blockIdx.x * 256 + threadIdx.x;   // 0..41471
    if (idx >= 40960) {                               // y-fragment region
        const int r  = idx - 40960;
        const int jj = r & 3;
        const int l  = (r >> 2) & 63;
        const int kk = (r >> 8) & 1;                  // 0 -> kt2, 1 -> kt3
        const int n  = l & 15;
        const int krow = ((l >> 4) << 3) + 2 * jj;
        const int ku   = 32 * kk + krow;              // h2 unit index
        h2 t;
        t[0] = (_Float16)((n == 0) ? Wlin[ku]     : 0.f);
        t[1] = (_Float16)((n == 0) ? Wlin[ku + 1] : 0.f);
        ws[idx] = __builtin_bit_cast(uint32_t, t);
        return;
    }
    int r, ktbits;
    const float *Wi = nullptr, *Wh;
    if (idx < 8192)       { r = idx;         ktbits = 1; Wh = Whh0; }
    else if (idx < 24576) { r = idx - 8192;  ktbits = 2; Wi = Wih1; Wh = Whh1; }
    else                  { r = idx - 24576; ktbits = 2; Wi = Wih2; Wh = Whh2; }
    const int jj  = r & 3;
    const int l   = (r >> 2) & 63;
    const int rem = r >> 8;
    const int kt  = rem & ((1 << ktbits) - 1);
    const int tw  = rem >> ktbits;
    const int j   = tw & 3;
    const int w   = tw >> 2;
    const int n   = l & 15;
    const int krow = ((l >> 4) << 3) + 2 * jj;
    const int orow = 64 * j + 16 * w + n;
    int kcol = 32 * kt + krow;
    const float* M;
    if (ktbits == 1)    { M = Wh; }
    else if (kcol < 64) { M = Wi; }
    else                { M = Wh; kcol -= 64; }
    h2 t;
    t[0] = (_Float16)M[orow * HH + kcol];
    t[1] = (_Float16)M[orow * HH + kcol + 1];
    ws[idx] = __builtin_bit_cast(uint32_t, t);
}

__global__ __launch_bounds__(768)
__attribute__((amdgpu_waves_per_eu(3)))
void lstm3_fused(
    const float* __restrict__ x,
    const float* __restrict__ Wih0,
    const float* __restrict__ bih0, const float* __restrict__ bhh0,
    const float* __restrict__ bih1, const float* __restrict__ bhh1,
    const float* __restrict__ bih2, const float* __restrict__ bhh2,
    const float* __restrict__ blin,
    const uint32_t* __restrict__ wpk,
    float* __restrict__ out)
{
    const int b    = blockIdx.x;
    const int tid  = threadIdx.x;
    const int grp  = tid >> 8;         // layer 0,1,2
    const int k    = tid & 255;
    const int w    = k >> 6;           // wave within group
    const int l    = k & 63;           // lane
    const int n    = l & 15;
    const int q    = l >> 4;           // 16-lane sub-group (A k-slice)
    const int unit = 16 * w + n;       // this lane's hidden unit
    const bool grp0w1 = (grp == 0) && (w == 1);   // head wave

    __shared__ __align__(16) float xrow[SQ + 8];
    __shared__ __align__(16) uint4 hbf[2][3][8];   // [buf][layer][64 fp16]
    __shared__ __align__(16) float ystage[32];     // head staging (1 wave)

    for (int i = tid; i < SQ; i += 768) xrow[i] = x[b * SQ + i];
    if (tid < 8) xrow[SQ + tid] = 0.f;
    if (tid < 48) ((uint4*)hbf)[tid] = make_uint4(0, 0, 0, 0);

    // ---- weights: MFMA B-fragments from workspace ----
    const int gbase = (grp == 0) ? 0 : (grp == 1) ? 8192 : 24576;
    const int KT    = (grp == 0) ? 2 : 4;
    const uint32_t* wbp = wpk + gbase;
    auto fr = [&](int j_, int kt_) {
        return *reinterpret_cast<const uint4*>(
            wbp + (((w * 4 + j_) * KT + kt_) * 64 + l) * 4);
    };
    uint4 w00 = fr(0, 0), w01 = fr(0, 1), w10 = fr(1, 0), w11 = fr(1, 1),
          w20 = fr(2, 0), w21 = fr(2, 1), w30 = fr(3, 0), w31 = fr(3, 1);
    pin4(w00); pin4(w01); pin4(w10); pin4(w11);
    pin4(w20); pin4(w21); pin4(w30); pin4(w31);
    uint4 w02 = {}, w03 = {}, w12 = {}, w13 = {},
          w22 = {}, w23 = {}, w32 = {}, w33 = {};
    if (grp != 0) {
        w02 = fr(0, 2); w03 = fr(0, 3); w12 = fr(1, 2); w13 = fr(1, 3);
        w22 = fr(2, 2); w23 = fr(2, 3); w32 = fr(3, 2); w33 = fr(3, 3);
        pin4(w02); pin4(w03); pin4(w12); pin4(w13);
        pin4(w22); pin4(w23); pin4(w32); pin4(w33);
    }
    // head fragments (grp0w1 only)
    uint4 wy2 = {}, wy3 = {};
    f32x4 cy = {0.f, 0.f, 0.f, 0.f};
    if (grp0w1) {
        wy2 = *reinterpret_cast<const uint4*>(wpk + 40960 + (0 * 64 + l) * 4);
        wy3 = *reinterpret_cast<const uint4*>(wpk + 40960 + (1 * 64 + l) * 4);
        pin4(wy2); pin4(wy3);
        const float bv = blin[0];
        cy = f32x4{bv, bv, bv, bv};
        pinv(cy);
    }

    // ---- persistent bias C-operands (gate j of unit -> row 64j + unit) ----
    const float* bi = (grp == 0) ? bih0 : (grp == 1) ? bih1 : bih2;
    const float* bh = (grp == 0) ? bhh0 : (grp == 1) ? bhh1 : bhh2;
    const float bs0 = bi[unit]       + bh[unit];
    const float bs1 = bi[64 + unit]  + bh[64 + unit];
    const float bs2 = bi[128 + unit] + bh[128 + unit];
    const float bs3 = bi[192 + unit] + bh[192 + unit];
    f32x4 cb0 = {bs0, bs0, bs0, bs0};  pinv(cb0);
    f32x4 cb1 = {bs1, bs1, bs1, bs1};  pinv(cb1);
    f32x4 cb2 = {bs2, bs2, bs2, bs2};  pinv(cb2);
    f32x4 cb3 = {bs3, bs3, bs3, bs3};  pinv(cb3);

    float wx0 = 0.f, wx1 = 0.f, wx2 = 0.f, wx3 = 0.f;
    if (grp == 0) {
        wx0 = Wih0[unit];       wx1 = Wih0[64 + unit];
        wx2 = Wih0[128 + unit]; wx3 = Wih0[192 + unit];
    }

    const int la = (grp == 2) ? 1 : 0;     // input-h source layer (A side)
    const int lb = grp;                    // own-h source layer (B side)
    const uint4* pA[2] = { &hbf[0][la][q], &hbf[1][la][q] };
    const uint4* pB[2] = { &hbf[0][lb][q], &hbf[1][lb][q] };
    const uint4* pY[2] = { &hbf[0][2][q],  &hbf[1][2][q] };   // head source
    _Float16* pH[2] = { (_Float16*)&hbf[0][grp][0] + unit,
                        (_Float16*)&hbf[1][grp][0] + unit };

    float cc = 0.f;                        // cell state (replicated all lanes)
    // carried input-side accumulators (grp1/2): acc_in(s) = Wih.h_in(s)+bias
    f32x4 ai0 = cb0, ai1 = cb1, ai2 = cb2, ai3 = cb3;

    __syncthreads();

    auto tick = [&](int T, int rd) {
        const int wr = rd ^ 1;
        float xT = 0.f;
        if (grp == 0) xT = xrow[T];        // padded; broadcast read

        f32x4 d0, d1, d2, d3;
        const uint4 a0 = pA[rd][0], a1 = pA[rd][4];
        if (grp == 0) {
            // single-sided: self matvec, step T
            d0 = mm(a0, w00, cb0);  d1 = mm(a0, w10, cb1);
            d2 = mm(a0, w20, cb2);  d3 = mm(a0, w30, cb3);
            d0 = mm(a1, w01, d0);   d1 = mm(a1, w11, d1);
            d2 = mm(a1, w21, d2);   d3 = mm(a1, w31, d3);
        } else {
            // finish step s = T-2*grp: self side (kt2,3) on carried acc_in
            const uint4 c0 = pB[rd][0], c1 = pB[rd][4];
            d0 = mm(c0, w02, ai0);  d1 = mm(c0, w12, ai1);
            d2 = mm(c0, w22, ai2);  d3 = mm(c0, w32, ai3);
            d0 = mm(c1, w03, d0);   d1 = mm(c1, w13, d1);
            d2 = mm(c1, w23, d2);   d3 = mm(c1, w33, d3);
            // prefetch input side (kt0,1) for step s+1 (h_in(s+1) published)
            ai0 = mm(a0, w00, cb0); ai1 = mm(a0, w10, cb1);
            ai2 = mm(a0, w20, cb2); ai3 = mm(a0, w30, cb3);
            ai0 = mm(a1, w01, ai0); ai1 = mm(a1, w11, ai1);
            ai2 = mm(a1, w21, ai2); ai3 = mm(a1, w31, ai3);
        }

        // ---- BRANCHLESS activation: all lanes, every tick ----
        const int step = T - 2 * grp;
        const bool valid = (step >= 0) && (step < SQ);

        float gi = d0[0], gf = d1[0], gg = d2[0], go = d3[0];
        if (grp == 0) {
            gi += wx0 * xT; gf += wx1 * xT;
            gg += wx2 * xT; go += wx3 * xT;
        }
        const float i_ = frcp(1.f + fexp2(gi * -1.44269504f));
        const float f_ = frcp(1.f + fexp2(gf * -1.44269504f));
        const float o_ = frcp(1.f + fexp2(go * -1.44269504f));
        const float tg = 2.f * frcp(1.f + fexp2(gg * -2.88539008f)) - 1.f;
        const float ncc = f_ * cc + i_ * tg;
        cc = valid ? ncc : cc;             // one v_cndmask, no branch
        const float tc = fminf(fmaxf(cc, -15.f), 15.f);
        const float e  = fexp2(tc * -2.88539008f);
        const float h  = o_ * ((1.f - e) * frcp(1.f + e));

        // ---- schedule choreography (grp1/2): interleave prefetch + act ----
        if (grp != 0) {
            __builtin_amdgcn_sched_group_barrier(0x100, 4, 0);  // 4 ds_read
            __builtin_amdgcn_sched_group_barrier(0x008, 8, 0);  // self MFMA
#pragma unroll
            for (int it = 0; it < 8; ++it) {
                __builtin_amdgcn_sched_group_barrier(0x008, 1, 0); // prefetch
                __builtin_amdgcn_sched_group_barrier(0x002, 5, 0); // act VALU
            }
        }

        if (valid && l < 16) {
            pH[wr][0] = (_Float16)h;
            if (step == SQ - 1) {
                out[NB * SQ + grp * NB * HH + b * HH + unit] = h;
                out[NB * SQ + 3 * NB * HH + grp * NB * HH + b * HH + unit] = cc;
            }
        }

        if (grp0w1) {
            // head: y(T-5) = Wlin . h2(T-5) + blin; h2(T-5) published age-1.
            const int sy = T - 5;
            if (sy >= 0 && sy < SQ) {
                const uint4 y0 = pY[rd][0], y1 = pY[rd][4];
                f32x4 d4 = mm(y0, wy2, cy);
                d4 = mm(y1, wy3, d4);
                if (l == 0) ystage[sy & 31] = d4[0];   // ds_write, lgkm-only
                if ((sy & 31) == 31) {
                    const float yv = ystage[l & 31];
                    if (l < 32) out[b * SQ + (sy - 31) + l] = yv;
                }
            }
        }
        __syncthreads();
    };

    // ticks 0..SQ+5 (l0 step=T, l1=T-2, l2=T-4, head y=T-5 -> needs T=SQ+4)
    for (int T = 0; T < SQ + 6; T += 2) {
        tick(T, 0);
        tick(T + 1, 1);
    }
}

extern "C" void kernel_launch(void* const* d_in, const int* in_sizes, int n_in,
                              void* d_out, int out_size, void* d_ws, size_t ws_size,
                              hipStream_t stream) {
    const float* x    = (const float*)d_in[0];
    const float* Wih0 = (const float*)d_in[1];
    const float* Whh0 = (const float*)d_in[2];
    const float* bih0 = (const float*)d_in[3];
    const float* bhh0 = (const float*)d_in[4];
    const float* Wih1 = (const float*)d_in[5];
    const float* Whh1 = (const float*)d_in[6];
    const float* bih1 = (const float*)d_in[7];
    const float* bhh1 = (const float*)d_in[8];
    const float* Wih2 = (const float*)d_in[9];
    const float* Whh2 = (const float*)d_in[10];
    const float* bih2 = (const float*)d_in[11];
    const float* bhh2 = (const float*)d_in[12];
    const float* Wlin = (const float*)d_in[13];
    const float* blin = (const float*)d_in[14];
    float* out = (float*)d_out;

    uint32_t* wpk = (uint32_t*)d_ws;   // 41472 u32 = 162 KiB < ws_size
    prep_weights<<<162, 256, 0, stream>>>(Whh0, Wih1, Whh1, Wih2, Whh2, Wlin, wpk);
    lstm3_fused<<<NB, 768, 0, stream>>>(x, Wih0, bih0, bhh0,
                                        bih1, bhh1, bih2, bhh2,
                                        blin, wpk, out);
}